// Round 5
// baseline (1260.338 us; speedup 1.0000x reference)
//
#include <hip/hip_runtime.h>
#include <hip/hip_bf16.h>

#define N_NODES 8192
#define IN_DIM  256
#define H_DIM   128
#define N_EDGES 262144

typedef __attribute__((ext_vector_type(8))) short bf16x8;
typedef __attribute__((ext_vector_type(4))) float f32x4;
typedef __attribute__((ext_vector_type(4))) short s16x4;

static __device__ inline short bf16_hi(float x) {
    __hip_bfloat16 h = __float2bfloat16(x);
    return *(short*)&h;
}
static __device__ inline float bf16_val(short s) {
    __hip_bfloat16 h = *(__hip_bfloat16*)&s;
    return __bfloat162float(h);
}

// ---------- degree + CSR build ----------
__global__ void hist_kernel(const int* __restrict__ src, const int* __restrict__ dst,
                            int* __restrict__ degc, int* __restrict__ dstc) {
    int e = blockIdx.x * 256 + threadIdx.x;
    if (e < N_EDGES) {
        atomicAdd(&degc[src[e]], 1);
        atomicAdd(&dstc[dst[e]], 1);
    }
}

__global__ void dinv_kernel(const int* __restrict__ degc, float* __restrict__ dinv) {
    int n = blockIdx.x * 256 + threadIdx.x;
    if (n < N_NODES) dinv[n] = 1.0f / sqrtf((float)(degc[n] + 1));
}

__global__ void scan_kernel(const int* __restrict__ cnt, int* __restrict__ rowptr,
                            int* __restrict__ cursor) {
    __shared__ int buf[2][256];
    int tid = threadIdx.x;
    const int chunk = N_NODES / 256;   // 32
    int base = tid * chunk;
    int s = 0;
    for (int i = 0; i < chunk; ++i) s += cnt[base + i];
    buf[0][tid] = s;
    __syncthreads();
    int pp = 0;
    for (int off = 1; off < 256; off <<= 1) {
        buf[pp ^ 1][tid] = buf[pp][tid] + (tid >= off ? buf[pp][tid - off] : 0);
        pp ^= 1;
        __syncthreads();
    }
    if (tid == 255) rowptr[N_NODES] = buf[pp][255];
    int run = buf[pp][tid] - s;        // exclusive prefix of per-thread partials
    for (int i = 0; i < chunk; ++i) {
        rowptr[base + i] = run;
        cursor[base + i] = run;
        run += cnt[base + i];
    }
}

__global__ void fill_kernel(const int* __restrict__ src, const int* __restrict__ dst,
                            int* __restrict__ cursor, int* __restrict__ colidx) {
    int e = blockIdx.x * 256 + threadIdx.x;
    if (e < N_EDGES) {
        int p = atomicAdd(&cursor[dst[e]], 1);
        colidx[p] = src[e];
    }
}

// ---------- split X (f32) into bf16 hi/lo ----------
__global__ __launch_bounds__(256) void cvtX_kernel(const f32x4* __restrict__ X,
                                                   s16x4* __restrict__ Xhi,
                                                   s16x4* __restrict__ Xlo) {
    int i = blockIdx.x * 256 + threadIdx.x;   // over N*IN/4 = 524288
    f32x4 x = X[i];
    s16x4 hi, lo;
#pragma unroll
    for (int j = 0; j < 4; ++j) {
        short h = bf16_hi(x[j]);
        hi[j] = h;
        lo[j] = bf16_hi(x[j] - bf16_val(h));
    }
    Xhi[i] = hi;
    Xlo[i] = lo;
}

// ---------- W^T split into bf16 hi/lo:  Wt[j][k] = W[k][j] ----------
__global__ __launch_bounds__(256) void cvtW_kernel(const float* __restrict__ W,
                                                   short* __restrict__ Wthi,
                                                   short* __restrict__ Wtlo) {
    int t = blockIdx.x * 256 + threadIdx.x;   // over 128*256 = 32768, k fastest
    int k = t & 255, j = t >> 8;
    float w = W[k * H_DIM + j];
    short h = bf16_hi(w);
    Wthi[t] = h;
    Wtlo[t] = bf16_hi(w - bf16_val(h));
}

// ---------- h = leaky_relu(X @ W + b) via split-bf16 MFMA; 32-row blocks ----------
__global__ __launch_bounds__(256) void gemm_h_mfma(const short* __restrict__ Xhi,
                                                   const short* __restrict__ Xlo,
                                                   const short* __restrict__ Wthi,
                                                   const short* __restrict__ Wtlo,
                                                   const float* __restrict__ b,
                                                   float* __restrict__ F0) {
    int lane = threadIdx.x & 63;
    int w    = threadIdx.x >> 6;
    int wr = w >> 1, wc = w & 1;          // 2x2 waves: 16 rows x 64 cols each
    int brow = blockIdx.x * 32 + wr * 16;
    int bcol = wc * 64;
    int r16 = lane & 15;
    int kg  = lane >> 4;

    f32x4 c[4] = {};
    for (int kk = 0; kk < IN_DIM / 32; ++kk) {   // 8
        int koff = kk * 32 + kg * 8;
        size_t aoff = (size_t)(brow + r16) * IN_DIM + koff;
        bf16x8 ah = *(const bf16x8*)(Xhi + aoff);
        bf16x8 al = *(const bf16x8*)(Xlo + aoff);
        bf16x8 bh[4], bl[4];
#pragma unroll
        for (int n = 0; n < 4; ++n) {
            size_t off = (size_t)(bcol + n * 16 + r16) * IN_DIM + koff;
            bh[n] = *(const bf16x8*)(Wthi + off);
            bl[n] = *(const bf16x8*)(Wtlo + off);
        }
#pragma unroll
        for (int n = 0; n < 4; ++n) {
            c[n] = __builtin_amdgcn_mfma_f32_16x16x32_bf16(ah, bh[n], c[n], 0, 0, 0);
            c[n] = __builtin_amdgcn_mfma_f32_16x16x32_bf16(ah, bl[n], c[n], 0, 0, 0);
            c[n] = __builtin_amdgcn_mfma_f32_16x16x32_bf16(al, bh[n], c[n], 0, 0, 0);
        }
    }
#pragma unroll
    for (int n = 0; n < 4; ++n)
#pragma unroll
        for (int r = 0; r < 4; ++r) {
            int row = brow + kg * 4 + r;       // C/D: row=(lane>>4)*4+reg (A side)
            int col = bcol + n * 16 + r16;     //      col=lane&15         (B side)
            float v = c[n][r] + b[col];
            v = v > 0.f ? v : 0.01f * v;
            F0[(size_t)row * H_DIM + col] = v;
        }
}

// ---------- one propagation step, tmp-free gather form ----------
__global__ __launch_bounds__(128) void prop_kernel(const float* __restrict__ Fin,
                                                   float* __restrict__ Fout,
                                                   const float* __restrict__ dinv,
                                                   const int* __restrict__ rowptr,
                                                   const int* __restrict__ colidx) {
    int n = blockIdx.x;
    int j = threadIdx.x;
    float dv  = dinv[n];
    float fs  = Fin[(size_t)n * H_DIM + j];
    float sum = fs * dv;                        // self loop
    int beg = rowptr[n], end = rowptr[n + 1];
    int e = beg;
    for (; e + 4 <= end; e += 4) {
        int s0 = colidx[e], s1 = colidx[e + 1], s2 = colidx[e + 2], s3 = colidx[e + 3];
        float d0 = dinv[s0], d1 = dinv[s1], d2 = dinv[s2], d3 = dinv[s3];
        float v0 = Fin[(size_t)s0 * H_DIM + j];
        float v1 = Fin[(size_t)s1 * H_DIM + j];
        float v2 = Fin[(size_t)s2 * H_DIM + j];
        float v3 = Fin[(size_t)s3 * H_DIM + j];
        sum += v0 * d0 + v1 * d1 + v2 * d2 + v3 * d3;
    }
    for (; e < end; ++e) {
        int s0 = colidx[e];
        sum += Fin[(size_t)s0 * H_DIM + j] * dinv[s0];
    }
    Fout[(size_t)n * H_DIM + j] = fs - sum * dv;
}

// ---------- acc_t = sum_k theta[t][k] * F_k, vectorized, cast to bf16 ----------
__global__ __launch_bounds__(256) void acc_kernel(const f32x4* __restrict__ F0,
                                                  const f32x4* __restrict__ F1,
                                                  const f32x4* __restrict__ F2,
                                                  const f32x4* __restrict__ F3,
                                                  s16x4* __restrict__ accb) {
    int i = blockIdx.x * 256 + threadIdx.x;        // over N*H/4 = 262144
    const size_t NH4 = (size_t)N_NODES * H_DIM / 4;
    f32x4 f0 = F0[i], f1 = F1[i], f2 = F2[i], f3 = F3[i];
    f32x4 a0 = 2.5f * f0 - 5.0f * f1 + 3.75f * f2 - 1.25f * f3;
    f32x4 a1 =           5.0f * f1 - 7.5f  * f2 + 3.75f * f3;
    f32x4 a2 =                      3.75f * f2 - 3.75f * f3;
    f32x4 a3 =                                   1.25f * f3;
    s16x4 o0, o1, o2, o3;
#pragma unroll
    for (int j = 0; j < 4; ++j) {
        o0[j] = bf16_hi(a0[j]); o1[j] = bf16_hi(a1[j]);
        o2[j] = bf16_hi(a2[j]); o3[j] = bf16_hi(a3[j]);
    }
    accb[0 * NH4 + i] = o0;
    accb[1 * NH4 + i] = o1;
    accb[2 * NH4 + i] = o2;
    accb[3 * NH4 + i] = o3;
}

// ---------- out_t = acc_t @ acc_t^T  (R3 variant; internally repeated `reps`
// times for attribution — opaque per-rep offset stops compute hoisting;
// stores are idempotent so output is unchanged) ----------
__global__ __launch_bounds__(256) void out_gemm_kernel(const short* __restrict__ accb,
                                                       float* __restrict__ out, int reps) {
    int t = blockIdx.z;
    int lane = threadIdx.x & 63;
    int w    = threadIdx.x >> 6;
    int wr = w >> 1, wc = w & 1;       // 2x2 waves, 64x64 each
    int brow = blockIdx.x * 128 + wr * 64;
    int bcol = blockIdx.y * 128 + wc * 64;
    int r16 = lane & 15;
    int kg  = lane >> 4;
    float* O = out + (size_t)t * N_NODES * N_NODES;

    for (int rep = 0; rep < reps; ++rep) {
        int zero = 0;
        asm volatile("" : "+v"(zero));            // fresh opaque 0 each rep
        const short* A = accb + (size_t)t * N_NODES * H_DIM + zero;

        f32x4 c[4][4] = {};
        for (int kk = 0; kk < 4; ++kk) {   // K = 128 in chunks of 32
            int koff = kk * 32 + kg * 8;
            bf16x8 a[4], bfr[4];
#pragma unroll
            for (int m = 0; m < 4; ++m)
                a[m] = *(const bf16x8*)(A + (size_t)(brow + m * 16 + r16) * H_DIM + koff);
#pragma unroll
            for (int n = 0; n < 4; ++n)
                bfr[n] = *(const bf16x8*)(A + (size_t)(bcol + n * 16 + r16) * H_DIM + koff);
#pragma unroll
            for (int m = 0; m < 4; ++m)
#pragma unroll
                for (int n = 0; n < 4; ++n)
                    c[m][n] = __builtin_amdgcn_mfma_f32_16x16x32_bf16(a[m], bfr[n], c[m][n], 0, 0, 0);
        }

        // Symmetric output -> store fragments transposed (f32x4 along the row), nt.
#pragma unroll
        for (int m = 0; m < 4; ++m)
#pragma unroll
            for (int n = 0; n < 4; ++n) {
                int col  = bcol + n * 16 + r16;
                int row0 = brow + m * 16 + kg * 4;
                __builtin_nontemporal_store(c[m][n], (f32x4*)(O + (size_t)col * N_NODES + row0));
            }
    }
}

extern "C" void kernel_launch(void* const* d_in, const int* in_sizes, int n_in,
                              void* d_out, int out_size, void* d_ws, size_t ws_size,
                              hipStream_t stream) {
    const float* in_feat = (const float*)d_in[0];
    const float* W       = (const float*)d_in[1];
    const float* b       = (const float*)d_in[2];
    const int*   src     = (const int*)d_in[3];
    const int*   dst     = (const int*)d_in[4];
    float* out = (float*)d_out;

    char* ws = (char*)d_ws;
    const size_t NH4 = (size_t)N_NODES * H_DIM * sizeof(float);   // 4 MB
    float* F0 = (float*)(ws + 0 * NH4);
    float* F1 = (float*)(ws + 1 * NH4);
    float* F2 = (float*)(ws + 2 * NH4);
    float* F3 = (float*)(ws + 3 * NH4);
    char*  accb_region = ws + 4 * NH4;                            // 8 MB
    short* accb = (short*)accb_region;
    short* Xhi = (short*)accb_region;                             // overlays accb (dead until acc)
    short* Xlo = (short*)(accb_region + NH4);
    char* p = ws + 6 * NH4;
    int*   degc   = (int*)p;   p += 32768;
    int*   dstc   = (int*)p;   p += 32768;
    float* dinv   = (float*)p; p += 32768;
    int*   rowptr = (int*)p;   p += 33792;   // N+1 ints, padded
    int*   cursor = (int*)p;   p += 32768;
    int*   colidx = (int*)p;   p += (size_t)N_EDGES * 4;          // 1 MB
    short* Wthi   = (short*)p; p += 65536;   // 128x256 bf16
    short* Wtlo   = (short*)p;

    hipMemsetAsync(degc, 0, 65536, stream);   // degc + dstc (adjacent)

    hist_kernel<<<N_EDGES / 256, 256, 0, stream>>>(src, dst, degc, dstc);
    dinv_kernel<<<N_NODES / 256, 256, 0, stream>>>(degc, dinv);
    scan_kernel<<<1, 256, 0, stream>>>(dstc, rowptr, cursor);
    fill_kernel<<<N_EDGES / 256, 256, 0, stream>>>(src, dst, cursor, colidx);

    cvtX_kernel<<<(N_NODES * IN_DIM / 4) / 256, 256, 0, stream>>>((const f32x4*)in_feat,
                                                                  (s16x4*)Xhi, (s16x4*)Xlo);
    cvtW_kernel<<<(H_DIM * IN_DIM) / 256, 256, 0, stream>>>(W, Wthi, Wtlo);

    gemm_h_mfma<<<N_NODES / 32, 256, 0, stream>>>(Xhi, Xlo, Wthi, Wtlo, b, F0);

    prop_kernel<<<N_NODES, 128, 0, stream>>>(F0, F1, dinv, rowptr, colidx);
    prop_kernel<<<N_NODES, 128, 0, stream>>>(F1, F2, dinv, rowptr, colidx);
    prop_kernel<<<N_NODES, 128, 0, stream>>>(F2, F3, dinv, rowptr, colidx);

    acc_kernel<<<(N_NODES * H_DIM / 4) / 256, 256, 0, stream>>>((const f32x4*)F0, (const f32x4*)F1,
                                                                (const f32x4*)F2, (const f32x4*)F3,
                                                                (s16x4*)accb);

    dim3 g(N_NODES / 128, N_NODES / 128, 4);
    out_gemm_kernel<<<g, 256, 0, stream>>>(accb, out, 4);
}

// Round 6
// 404.304 us; speedup vs baseline: 3.1173x; 3.1173x over previous
//
#include <hip/hip_runtime.h>
#include <hip/hip_bf16.h>

#define N_NODES 8192
#define IN_DIM  256
#define H_DIM   128
#define N_EDGES 262144
#define BI 64
#define BJ 256

typedef __attribute__((ext_vector_type(8))) short bf16x8;
typedef __attribute__((ext_vector_type(4))) float f32x4;
typedef __attribute__((ext_vector_type(4))) short s16x4;

static __device__ inline short bf16_hi(float x) {
    __hip_bfloat16 h = __float2bfloat16(x);
    return *(short*)&h;
}
static __device__ inline float bf16_val(short s) {
    __hip_bfloat16 h = *(__hip_bfloat16*)&s;
    return __bfloat162float(h);
}

// ---------- degree + CSR build ----------
__global__ void hist_kernel(const int* __restrict__ src, const int* __restrict__ dst,
                            int* __restrict__ degc, int* __restrict__ dstc) {
    int e = blockIdx.x * 256 + threadIdx.x;
    if (e < N_EDGES) {
        atomicAdd(&degc[src[e]], 1);
        atomicAdd(&dstc[dst[e]], 1);
    }
}

__global__ void dinv_kernel(const int* __restrict__ degc, float* __restrict__ dinv) {
    int n = blockIdx.x * 256 + threadIdx.x;
    if (n < N_NODES) dinv[n] = 1.0f / sqrtf((float)(degc[n] + 1));
}

__global__ void scan_kernel(const int* __restrict__ cnt, int* __restrict__ rowptr,
                            int* __restrict__ cursor) {
    __shared__ int buf[2][256];
    int tid = threadIdx.x;
    const int chunk = N_NODES / 256;   // 32
    int base = tid * chunk;
    int s = 0;
    for (int i = 0; i < chunk; ++i) s += cnt[base + i];
    buf[0][tid] = s;
    __syncthreads();
    int pp = 0;
    for (int off = 1; off < 256; off <<= 1) {
        buf[pp ^ 1][tid] = buf[pp][tid] + (tid >= off ? buf[pp][tid - off] : 0);
        pp ^= 1;
        __syncthreads();
    }
    if (tid == 255) rowptr[N_NODES] = buf[pp][255];
    int run = buf[pp][tid] - s;        // exclusive prefix of per-thread partials
    for (int i = 0; i < chunk; ++i) {
        rowptr[base + i] = run;
        cursor[base + i] = run;
        run += cnt[base + i];
    }
}

__global__ void fill_kernel(const int* __restrict__ src, const int* __restrict__ dst,
                            int* __restrict__ cursor, int* __restrict__ colidx) {
    int e = blockIdx.x * 256 + threadIdx.x;
    if (e < N_EDGES) {
        int p = atomicAdd(&cursor[dst[e]], 1);
        colidx[p] = src[e];
    }
}

// ---------- split X (f32) into bf16 hi/lo ----------
__global__ __launch_bounds__(256) void cvtX_kernel(const f32x4* __restrict__ X,
                                                   s16x4* __restrict__ Xhi,
                                                   s16x4* __restrict__ Xlo) {
    int i = blockIdx.x * 256 + threadIdx.x;   // over N*IN/4 = 524288
    f32x4 x = X[i];
    s16x4 hi, lo;
#pragma unroll
    for (int j = 0; j < 4; ++j) {
        short h = bf16_hi(x[j]);
        hi[j] = h;
        lo[j] = bf16_hi(x[j] - bf16_val(h));
    }
    Xhi[i] = hi;
    Xlo[i] = lo;
}

// ---------- W^T split into bf16 hi/lo:  Wt[j][k] = W[k][j] ----------
__global__ __launch_bounds__(256) void cvtW_kernel(const float* __restrict__ W,
                                                   short* __restrict__ Wthi,
                                                   short* __restrict__ Wtlo) {
    int t = blockIdx.x * 256 + threadIdx.x;   // over 128*256 = 32768, k fastest
    int k = t & 255, j = t >> 8;
    float w = W[k * H_DIM + j];
    short h = bf16_hi(w);
    Wthi[t] = h;
    Wtlo[t] = bf16_hi(w - bf16_val(h));
}

// ---------- h = leaky_relu(X @ W + b) via split-bf16 MFMA; 32-row blocks ----------
__global__ __launch_bounds__(256) void gemm_h_mfma(const short* __restrict__ Xhi,
                                                   const short* __restrict__ Xlo,
                                                   const short* __restrict__ Wthi,
                                                   const short* __restrict__ Wtlo,
                                                   const float* __restrict__ b,
                                                   float* __restrict__ F0) {
    int lane = threadIdx.x & 63;
    int w    = threadIdx.x >> 6;
    int wr = w >> 1, wc = w & 1;          // 2x2 waves: 16 rows x 64 cols each
    int brow = blockIdx.x * 32 + wr * 16;
    int bcol = wc * 64;
    int r16 = lane & 15;
    int kg  = lane >> 4;

    f32x4 c[4] = {};
    for (int kk = 0; kk < IN_DIM / 32; ++kk) {   // 8
        int koff = kk * 32 + kg * 8;
        size_t aoff = (size_t)(brow + r16) * IN_DIM + koff;
        bf16x8 ah = *(const bf16x8*)(Xhi + aoff);
        bf16x8 al = *(const bf16x8*)(Xlo + aoff);
        bf16x8 bh[4], bl[4];
#pragma unroll
        for (int n = 0; n < 4; ++n) {
            size_t off = (size_t)(bcol + n * 16 + r16) * IN_DIM + koff;
            bh[n] = *(const bf16x8*)(Wthi + off);
            bl[n] = *(const bf16x8*)(Wtlo + off);
        }
#pragma unroll
        for (int n = 0; n < 4; ++n) {
            c[n] = __builtin_amdgcn_mfma_f32_16x16x32_bf16(ah, bh[n], c[n], 0, 0, 0);
            c[n] = __builtin_amdgcn_mfma_f32_16x16x32_bf16(ah, bl[n], c[n], 0, 0, 0);
            c[n] = __builtin_amdgcn_mfma_f32_16x16x32_bf16(al, bh[n], c[n], 0, 0, 0);
        }
    }
#pragma unroll
    for (int n = 0; n < 4; ++n)
#pragma unroll
        for (int r = 0; r < 4; ++r) {
            int row = brow + kg * 4 + r;       // C/D: row=(lane>>4)*4+reg (A side)
            int col = bcol + n * 16 + r16;     //      col=lane&15         (B side)
            float v = c[n][r] + b[col];
            v = v > 0.f ? v : 0.01f * v;
            F0[(size_t)row * H_DIM + col] = v;
        }
}

// ---------- one propagation step, tmp-free gather form ----------
__global__ __launch_bounds__(128) void prop_kernel(const float* __restrict__ Fin,
                                                   float* __restrict__ Fout,
                                                   const float* __restrict__ dinv,
                                                   const int* __restrict__ rowptr,
                                                   const int* __restrict__ colidx) {
    int n = blockIdx.x;
    int j = threadIdx.x;
    float dv  = dinv[n];
    float fs  = Fin[(size_t)n * H_DIM + j];
    float sum = fs * dv;                        // self loop
    int beg = rowptr[n], end = rowptr[n + 1];
    int e = beg;
    for (; e + 4 <= end; e += 4) {
        int s0 = colidx[e], s1 = colidx[e + 1], s2 = colidx[e + 2], s3 = colidx[e + 3];
        float d0 = dinv[s0], d1 = dinv[s1], d2 = dinv[s2], d3 = dinv[s3];
        float v0 = Fin[(size_t)s0 * H_DIM + j];
        float v1 = Fin[(size_t)s1 * H_DIM + j];
        float v2 = Fin[(size_t)s2 * H_DIM + j];
        float v3 = Fin[(size_t)s3 * H_DIM + j];
        sum += v0 * d0 + v1 * d1 + v2 * d2 + v3 * d3;
    }
    for (; e < end; ++e) {
        int s0 = colidx[e];
        sum += Fin[(size_t)s0 * H_DIM + j] * dinv[s0];
    }
    Fout[(size_t)n * H_DIM + j] = fs - sum * dv;
}

// ---------- acc_t = sum_k theta[t][k] * F_k, vectorized, cast to bf16 ----------
__global__ __launch_bounds__(256) void acc_kernel(const f32x4* __restrict__ F0,
                                                  const f32x4* __restrict__ F1,
                                                  const f32x4* __restrict__ F2,
                                                  const f32x4* __restrict__ F3,
                                                  s16x4* __restrict__ accb) {
    int i = blockIdx.x * 256 + threadIdx.x;        // over N*H/4 = 262144
    const size_t NH4 = (size_t)N_NODES * H_DIM / 4;
    f32x4 f0 = F0[i], f1 = F1[i], f2 = F2[i], f3 = F3[i];
    f32x4 a0 = 2.5f * f0 - 5.0f * f1 + 3.75f * f2 - 1.25f * f3;
    f32x4 a1 =           5.0f * f1 - 7.5f  * f2 + 3.75f * f3;
    f32x4 a2 =                      3.75f * f2 - 3.75f * f3;
    f32x4 a3 =                                   1.25f * f3;
    s16x4 o0, o1, o2, o3;
#pragma unroll
    for (int j = 0; j < 4; ++j) {
        o0[j] = bf16_hi(a0[j]); o1[j] = bf16_hi(a1[j]);
        o2[j] = bf16_hi(a2[j]); o3[j] = bf16_hi(a3[j]);
    }
    accb[0 * NH4 + i] = o0;
    accb[1 * NH4 + i] = o1;
    accb[2 * NH4 + i] = o2;
    accb[3 * NH4 + i] = o3;
}

// ---------- out_t = acc_t @ acc_t^T — I=64 x J=256 tile, LDS-staged linear writes ----
// Compute with A-operand = J-side rows (verified R4 mapping: D[j][i], j on reg axis),
// stage the 64x256 f32 tile in LDS (XOR bank swizzle), then stream 1KB-contiguous
// nontemporal stores per wave-instruction (symmetric output -> store D[j][i] at O[i][j]).
__global__ __launch_bounds__(256) void out_gemm_kernel(const short* __restrict__ accb,
                                                       float* __restrict__ out) {
    __shared__ float lds[BI * BJ];            // 64 KB
    int t = blockIdx.z;
    const short* A = accb + (size_t)t * N_NODES * H_DIM;
    int lane = threadIdx.x & 63;
    int w    = threadIdx.x >> 6;              // 0..3: 64-wide J strip per wave
    int ib = blockIdx.y * BI;
    int jb = blockIdx.x * BJ;
    int r16 = lane & 15;
    int kg  = lane >> 4;

    f32x4 c[4][4] = {};
    for (int kk = 0; kk < 4; ++kk) {          // K = 128 in chunks of 32
        int koff = kk * 32 + kg * 8;
        bf16x8 bi_f[4], aj_f[4];
#pragma unroll
        for (int n = 0; n < 4; ++n)           // I-side rows (B operand)
            bi_f[n] = *(const bf16x8*)(A + (size_t)(ib + n * 16 + r16) * H_DIM + koff);
#pragma unroll
        for (int m = 0; m < 4; ++m)           // J-side rows (A operand)
            aj_f[m] = *(const bf16x8*)(A + (size_t)(jb + w * 64 + m * 16 + r16) * H_DIM + koff);
#pragma unroll
        for (int m = 0; m < 4; ++m)
#pragma unroll
            for (int n = 0; n < 4; ++n)
                c[m][n] = __builtin_amdgcn_mfma_f32_16x16x32_bf16(aj_f[m], bi_f[n], c[m][n], 0, 0, 0);
    }

    // D fragment: j_local = w*64 + m*16 + kg*4 + reg, i_local = n*16 + r16.
    // LDS layout: float at logical (i,j) lives at i*BJ + (j ^ ((i&7)<<2)).
#pragma unroll
    for (int m = 0; m < 4; ++m)
#pragma unroll
        for (int n = 0; n < 4; ++n) {
            int i  = n * 16 + r16;
            int j  = w * 64 + m * 16 + kg * 4;
            int js = j ^ ((i & 7) << 2);
            *(f32x4*)(lds + i * BJ + js) = c[m][n];
        }
    __syncthreads();

    // Linear readout: 16 passes x 4 waves = 64 rows; each wave stores 1KB contiguous.
    float* O = out + (size_t)t * N_NODES * N_NODES;
#pragma unroll
    for (int p = 0; p < 16; ++p) {
        int r  = p * 4 + w;
        f32x4 v = *(const f32x4*)(lds + r * BJ + lane * 4);
        int jl = (lane * 4) ^ ((r & 7) << 2);     // logical j of this phys slot
        __builtin_nontemporal_store(v, (f32x4*)(O + (size_t)(ib + r) * N_NODES + jb + jl));
    }
}

extern "C" void kernel_launch(void* const* d_in, const int* in_sizes, int n_in,
                              void* d_out, int out_size, void* d_ws, size_t ws_size,
                              hipStream_t stream) {
    const float* in_feat = (const float*)d_in[0];
    const float* W       = (const float*)d_in[1];
    const float* b       = (const float*)d_in[2];
    const int*   src     = (const int*)d_in[3];
    const int*   dst     = (const int*)d_in[4];
    float* out = (float*)d_out;

    char* ws = (char*)d_ws;
    const size_t NH4 = (size_t)N_NODES * H_DIM * sizeof(float);   // 4 MB
    float* F0 = (float*)(ws + 0 * NH4);
    float* F1 = (float*)(ws + 1 * NH4);
    float* F2 = (float*)(ws + 2 * NH4);
    float* F3 = (float*)(ws + 3 * NH4);
    char*  accb_region = ws + 4 * NH4;                            // 8 MB
    short* accb = (short*)accb_region;
    short* Xhi = (short*)accb_region;                             // overlays accb (dead until acc)
    short* Xlo = (short*)(accb_region + NH4);
    char* p = ws + 6 * NH4;
    int*   degc   = (int*)p;   p += 32768;
    int*   dstc   = (int*)p;   p += 32768;
    float* dinv   = (float*)p; p += 32768;
    int*   rowptr = (int*)p;   p += 33792;   // N+1 ints, padded
    int*   cursor = (int*)p;   p += 32768;
    int*   colidx = (int*)p;   p += (size_t)N_EDGES * 4;          // 1 MB
    short* Wthi   = (short*)p; p += 65536;   // 128x256 bf16
    short* Wtlo   = (short*)p;

    hipMemsetAsync(degc, 0, 65536, stream);   // degc + dstc (adjacent)

    hist_kernel<<<N_EDGES / 256, 256, 0, stream>>>(src, dst, degc, dstc);
    dinv_kernel<<<N_NODES / 256, 256, 0, stream>>>(degc, dinv);
    scan_kernel<<<1, 256, 0, stream>>>(dstc, rowptr, cursor);
    fill_kernel<<<N_EDGES / 256, 256, 0, stream>>>(src, dst, cursor, colidx);

    cvtX_kernel<<<(N_NODES * IN_DIM / 4) / 256, 256, 0, stream>>>((const f32x4*)in_feat,
                                                                  (s16x4*)Xhi, (s16x4*)Xlo);
    cvtW_kernel<<<(H_DIM * IN_DIM) / 256, 256, 0, stream>>>(W, Wthi, Wtlo);

    gemm_h_mfma<<<N_NODES / 32, 256, 0, stream>>>(Xhi, Xlo, Wthi, Wtlo, b, F0);

    prop_kernel<<<N_NODES, 128, 0, stream>>>(F0, F1, dinv, rowptr, colidx);
    prop_kernel<<<N_NODES, 128, 0, stream>>>(F1, F2, dinv, rowptr, colidx);
    prop_kernel<<<N_NODES, 128, 0, stream>>>(F2, F3, dinv, rowptr, colidx);

    acc_kernel<<<(N_NODES * H_DIM / 4) / 256, 256, 0, stream>>>((const f32x4*)F0, (const f32x4*)F1,
                                                                (const f32x4*)F2, (const f32x4*)F3,
                                                                (s16x4*)accb);

    dim3 g(N_NODES / BJ, N_NODES / BI, 4);
    out_gemm_kernel<<<g, 256, 0, stream>>>(accb, out);
}